// Round 12
// baseline (135.374 us; speedup 1.0000x reference)
//
#include <hip/hip_runtime.h>

// CRS rate-and-state model. R -> et*R/(1+c*R) is a Mobius map [[a,0],[c,1]];
// maps compose associatively -> whole T=4096 row is ONE two-level scan.
// R12 = R11 (126us) with TWO ROWS PER BLOCK, software-pipelined.
// R11's decisive data: traffic -12% (R9->R11) moved time only -1.5% -> not
// BW-bound; memory-time (~75us) + VALU-time (~53us) ~= measured 126us ->
// the pipes are NOT overlapping (barrier-separated serial phases per block).
// Fix: 4096 blocks x 512 thr, rows {2b,2b+1}. Both rows' loads issue at the
// top (12x dwordx4, max MLP); row1's loads hide under row0's entire
// compute+scan+store pipeline; row0's nt stores drain under row1's compute.
// asm "+v" pin after row0 stops LLVM sinking row1's loads (R2/R4 failure).
// Keeps R11's proven machinery: dual skewed LDS bounce (lane-contiguous
// store instructions - R10 showed per-thread-contiguous nt stores 3.2x WRITE
// amplification), per-row phase shift -> 64B-aligned f4 nt stores.

#define C_TNSR  0.001f
#define C_TSSR  0.002f
#define C_SIGMA 50.0f
#define C_BIOT  0.3f
#define C_R0    0.0001f
#define C_N0    0.0001f

constexpr int B = 8192;
constexpr int T = 4096;
constexpr int STEPS = 8;           // per lane
constexpr int NTHR  = 512;         // threads per block
constexpr int WAVES = NTHR / 64;   // 8

typedef float f4 __attribute__((ext_vector_type(4)));

__device__ __forceinline__ int SIDX(int m) { return m + (m >> 5); }

struct SharedBuf {
    float lsR[T + T / 32];
    float lsN[T + T / 32];
    float sA[WAVES], sC[WAVES], sS[WAVES];
};

__device__ __forceinline__ void do_row(
    int b, int tid, int lane, int wid,
    float mu, float rc, float rf,
    f4 pv0, f4 pv1, f4 dv0, f4 dv1, f4 tv0, f4 tv1,
    SharedBuf* sh, float* __restrict__ Rt, float* __restrict__ Nt)
{
    const float eta = 1.0f / rf;
    const float rcS = rc * C_SIGMA;
    const float rcB = rc * C_BIOT;
    const int seg = tid * STEPS;

    // ---- phase 1: per-lane inclusive Mobius prefixes ----
    float Aj[STEPS], Cj[STEPS], kk[STEPS];
    float A = 1.0f, C = 0.0f;
#pragma unroll
    for (int j = 0; j < STEPS; ++j) {
        float pp = (j < 4) ? pv0[j] : pv1[j - 4];
        float dd = (j < 4) ? dv0[j] : dv1[j - 4];
        float tt = (j < 4) ? tv0[j] : tv1[j - 4];
        float sd   = C_TSSR - mu * (C_TNSR - dd);
        float asig = fmaf(-rcB, pp, rcS);
        float e    = __expf(__fdividef(sd * tt, asig));
        float c    = __fdividef(eta * (e - 1.0f), sd);
        kk[j] = asig * rf;               // asig/eta
        C = fmaf(c, A, C);               // compose step j after (A,C)
        A = A * e;
        Aj[j] = A;
        Cj[j] = C;
    }

    // ---- phase 2a: wave-inclusive scan of (A,C) ----
#pragma unroll
    for (int o = 1; o < 64; o <<= 1) {
        float Ap = __shfl_up(A, (unsigned)o, 64);
        float Cp = __shfl_up(C, (unsigned)o, 64);
        if (lane >= o) { C = fmaf(C, Ap, Cp); A = A * Ap; }
    }
    float Ae = __shfl_up(A, 1u, 64);
    float Ce = __shfl_up(C, 1u, 64);
    if (lane == 0) { Ae = 1.0f; Ce = 0.0f; }

    // ---- phase 2b: cross-wave composition via LDS ----
    if (lane == 63) { sh->sA[wid] = A; sh->sC[wid] = C; }
    __syncthreads();                                   // bar 1
    float PA = 1.0f, PC = 0.0f;
#pragma unroll
    for (int w = 0; w < WAVES - 1; ++w) {
        if (w < wid) { PC = fmaf(sh->sC[w], PA, PC); PA = sh->sA[w] * PA; }
    }
    float EA = Ae * PA;
    float EC = fmaf(Ce, PA, PC);
    float Rt_ = __fdividef(EA * C_R0, fmaf(EC, C_R0, 1.0f));   // R entering segment

    // ---- phase 3: closed-form outputs; den telescopes ----
    float nn[STEPS];
    float ns = 0.0f;
    float rlPrev = 1.0f;
#pragma unroll
    for (int j = 0; j < STEPS; ++j) {
        float L   = fmaf(Cj[j], Rt_, 1.0f);
        float rlj = __fdividef(1.0f, L);
        sh->lsR[SIDX(seg + j)] = (Aj[j] * Rt_) * rlj;
        float den = L * rlPrev;                        // == 1 + c_j*R_{j-1}
        ns += kk[j] * __logf(den);
        nn[j] = ns;
        rlPrev = rlj;
    }

    // ---- phase 4: two-level prefix sum of per-lane N totals ----
    float S = ns;
#pragma unroll
    for (int o = 1; o < 64; o <<= 1) {
        float Sp = __shfl_up(S, (unsigned)o, 64);
        if (lane >= o) S += Sp;
    }
    if (lane == 63) sh->sS[wid] = S;
    __syncthreads();                                   // bar 2
    float PS = C_N0;
#pragma unroll
    for (int w = 0; w < WAVES - 1; ++w) {
        if (w < wid) PS += sh->sS[w];
    }
    float base = PS + (S - ns);
#pragma unroll
    for (int j = 0; j < STEPS; ++j)
        sh->lsN[SIDX(seg + j)] = base + nn[j];

    __syncthreads();                                   // bar 3

    // ---- aligned store stage (all global stores NONTEMPORAL) ----
    const size_t g0 = (size_t)b * (T + 1) + 1;         // dword index of step 0
    const int s  = (int)((16 - (g0 & 15)) & 15);       // shift to 64B boundary
    const int tl = (T - s) & 3;                        // tail dwords
    const int bodyEnd = T - tl;

    if (tid == 0) {
        __builtin_nontemporal_store(C_R0, Rt + g0 - 1);
        __builtin_nontemporal_store(C_N0, Nt + g0 - 1);
    }
    if (tid < s) {
        __builtin_nontemporal_store(sh->lsR[SIDX(tid)], Rt + g0 + tid);
        __builtin_nontemporal_store(sh->lsN[SIDX(tid)], Nt + g0 + tid);
    }
    if (tid < tl) {
        int m = bodyEnd + tid;
        __builtin_nontemporal_store(sh->lsR[SIDX(m)], Rt + g0 + m);
        __builtin_nontemporal_store(sh->lsN[SIDX(m)], Nt + g0 + m);
    }

#pragma unroll
    for (int q = 0; q < 2; ++q) {                      // body: 64B-aligned f4
        int m0 = s + q * 2048 + tid * 4;
        if (m0 + 4 <= bodyEnd) {
            f4 r, n;
#pragma unroll
            for (int c = 0; c < 4; ++c) {
                r[c] = sh->lsR[SIDX(m0 + c)];
                n[c] = sh->lsN[SIDX(m0 + c)];
            }
            __builtin_nontemporal_store(r, (f4*)(Rt + g0 + m0));
            __builtin_nontemporal_store(n, (f4*)(Nt + g0 + m0));
        }
    }
}

__global__ __launch_bounds__(NTHR, 4)
void crs_row2_kernel(const float* __restrict__ params,
                     const float* __restrict__ p,
                     const float* __restrict__ dpdt,
                     const float* __restrict__ dtv,
                     float* __restrict__ Rt,
                     float* __restrict__ Nt)
{
    __shared__ SharedBuf sh;

    const int tid  = threadIdx.x;
    const int lane = tid & 63;
    const int wid  = tid >> 6;
    const int b0   = blockIdx.x * 2;
    const int b1   = b0 + 1;

    const float mu0 = params[b0 * 3 + 0];
    const float rc0 = params[b0 * 3 + 1];
    const float rf0 = params[b0 * 3 + 2];
    const float mu1 = params[b1 * 3 + 0];
    const float rc1 = params[b1 * 3 + 1];
    const float rf1 = params[b1 * 3 + 2];

    const int seg = tid * STEPS;
    const float* pr0 = p    + (size_t)b0 * T + seg;
    const float* dr0 = dpdt + (size_t)b0 * T + seg;
    const float* tr0 = dtv  + (size_t)b0 * T + seg;
    const float* pr1 = p    + (size_t)b1 * T + seg;
    const float* dr1 = dpdt + (size_t)b1 * T + seg;
    const float* tr1 = dtv  + (size_t)b1 * T + seg;

    // ---- issue BOTH rows' loads upfront (12 x dwordx4, max MLP) ----
    f4 a_pv0 = *(const f4*)(pr0);
    f4 a_pv1 = *(const f4*)(pr0 + 4);
    f4 a_dv0 = *(const f4*)(dr0);
    f4 a_dv1 = *(const f4*)(dr0 + 4);
    f4 a_tv0 = *(const f4*)(tr0);
    f4 a_tv1 = *(const f4*)(tr0 + 4);
    f4 b_pv0 = *(const f4*)(pr1);
    f4 b_pv1 = *(const f4*)(pr1 + 4);
    f4 b_dv0 = *(const f4*)(dr1);
    f4 b_dv1 = *(const f4*)(dr1 + 4);
    f4 b_tv0 = *(const f4*)(tr1);
    f4 b_tv1 = *(const f4*)(tr1 + 4);
    __builtin_amdgcn_sched_barrier(0);

    // ---- row 0: full pipeline (row 1's loads land underneath) ----
    do_row(b0, tid, lane, wid, mu0, rc0, rf0,
           a_pv0, a_pv1, a_dv0, a_dv1, a_tv0, a_tv1, &sh, Rt, Nt);

    // pin row 1's vectors: forces materialization here, stops load sinking
    asm volatile("" : "+v"(b_pv0), "+v"(b_pv1), "+v"(b_dv0),
                      "+v"(b_dv1), "+v"(b_tv0), "+v"(b_tv1));

    // ---- row 1: its stores drain as the block retires ----
    do_row(b1, tid, lane, wid, mu1, rc1, rf1,
           b_pv0, b_pv1, b_dv0, b_dv1, b_tv0, b_tv1, &sh, Rt, Nt);
}

extern "C" void kernel_launch(void* const* d_in, const int* in_sizes, int n_in,
                              void* d_out, int out_size, void* d_ws, size_t ws_size,
                              hipStream_t stream)
{
    const float* params = (const float*)d_in[0];
    const float* p      = (const float*)d_in[1];
    const float* dpdt   = (const float*)d_in[2];
    const float* dtv    = (const float*)d_in[3];

    float* Rt = (float*)d_out;                       // B*(T+1)
    float* Nt = (float*)d_out + (size_t)B * (T + 1); // B*(T+1)

    crs_row2_kernel<<<B / 2, NTHR, 0, stream>>>(params, p, dpdt, dtv, Rt, Nt);
}

// Round 14
// 133.490 us; speedup vs baseline: 1.0141x; 1.0141x over previous
//
#include <hip/hip_runtime.h>

// CRS rate-and-state model. R -> et*R/(1+c*R) is a Mobius map [[a,0],[c,1]];
// maps compose associatively -> whole T=4096 row is ONE two-level scan.
// R14 = R13 (asm-pipelined two rows/block) minus its three crash hazards:
//  1. NO d_ws scratch redirect (R13 likely faulted on it): body stores are
//     if(ok)-conditional again; every wave still issues exactly 4 body
//     stores (exec nonzero in all waves for both q slices) so the counted
//     vmcnt ledger stays exact.
//  2. "=&v" early-clobber on async global_load outputs.
//  3. sched_barrier(0) after every counted s_waitcnt (guide rule #18:
//     register-only reads hoist past inline-asm waitcnt otherwise).
// Pipeline (per thread, vmem issue order is exact by construction):
//   [drain vmcnt(0) lgkmcnt(0)]  L0..L5(row0)  L6..L11(row1)
//   vmcnt(6)+SB0  -> row0 ready; row1 loads stay in flight under row0 work
//   row0 compute (lgkm-only barriers; __syncthreads would drain vmcnt(0))
//   row0 body stores (4/wave)  ->  vmcnt(4)+SB0 -> row1 loads retired
//   row0 edges; row1 compute; row1 stores.
// Keeps R11's proven machinery: dual skewed LDS bounce (per-WAVE-INSTRUCTION
// lane contiguity; R10: per-thread-contiguous nt stores = 3.2x WRITE ampl),
// per-row phase shift -> 64B-aligned f4 nt stores (R6 RMW + R9 L3 wins).

#define C_TNSR  0.001f
#define C_TSSR  0.002f
#define C_SIGMA 50.0f
#define C_BIOT  0.3f
#define C_R0    0.0001f
#define C_N0    0.0001f

constexpr int B = 8192;
constexpr int T = 4096;
constexpr int STEPS = 8;           // per lane
constexpr int NTHR  = 512;         // threads per block
constexpr int WAVES = NTHR / 64;   // 8

typedef float f4 __attribute__((ext_vector_type(4)));

__device__ __forceinline__ int SIDX(int m) { return m + (m >> 5); }

struct SharedBuf {
    float lsR[T + T / 32];
    float lsN[T + T / 32];
    float sA[WAVES], sC[WAVES], sS[WAVES];
};

// workgroup barrier WITHOUT the compiler's vmcnt(0) drain (LDS-only ordering)
__device__ __forceinline__ void barrier_lgkm() {
    asm volatile("s_waitcnt lgkmcnt(0)\n\ts_barrier" ::: "memory");
}

#define GLOAD(dst, ptr)     asm volatile("global_load_dwordx4 %0, %1, off"           : "=&v"(dst) : "v"(ptr))
#define GLOAD16(dst, ptr)   asm volatile("global_load_dwordx4 %0, %1, off offset:16" : "=&v"(dst) : "v"(ptr))

__device__ __forceinline__ void compute_row(
    int tid, int lane, int wid,
    float mu, float rc, float rf,
    f4 pv0, f4 pv1, f4 dv0, f4 dv1, f4 tv0, f4 tv1,
    SharedBuf* sh)
{
    const float eta = 1.0f / rf;
    const float rcS = rc * C_SIGMA;
    const float rcB = rc * C_BIOT;
    const int seg = tid * STEPS;

    // ---- phase 1: per-lane inclusive Mobius prefixes ----
    float Aj[STEPS], Cj[STEPS], kk[STEPS];
    float A = 1.0f, C = 0.0f;
#pragma unroll
    for (int j = 0; j < STEPS; ++j) {
        float pp = (j < 4) ? pv0[j] : pv1[j - 4];
        float dd = (j < 4) ? dv0[j] : dv1[j - 4];
        float tt = (j < 4) ? tv0[j] : tv1[j - 4];
        float sd   = C_TSSR - mu * (C_TNSR - dd);
        float asig = fmaf(-rcB, pp, rcS);
        float e    = __expf(__fdividef(sd * tt, asig));
        float c    = __fdividef(eta * (e - 1.0f), sd);
        kk[j] = asig * rf;               // asig/eta
        C = fmaf(c, A, C);               // compose step j after (A,C)
        A = A * e;
        Aj[j] = A;
        Cj[j] = C;
    }

    // ---- phase 2a: wave-inclusive scan of (A,C) ----
#pragma unroll
    for (int o = 1; o < 64; o <<= 1) {
        float Ap = __shfl_up(A, (unsigned)o, 64);
        float Cp = __shfl_up(C, (unsigned)o, 64);
        if (lane >= o) { C = fmaf(C, Ap, Cp); A = A * Ap; }
    }
    float Ae = __shfl_up(A, 1u, 64);
    float Ce = __shfl_up(C, 1u, 64);
    if (lane == 0) { Ae = 1.0f; Ce = 0.0f; }

    // ---- phase 2b: cross-wave composition via LDS ----
    if (lane == 63) { sh->sA[wid] = A; sh->sC[wid] = C; }
    barrier_lgkm();                                    // bar 1
    float PA = 1.0f, PC = 0.0f;
#pragma unroll
    for (int w = 0; w < WAVES - 1; ++w) {
        if (w < wid) { PC = fmaf(sh->sC[w], PA, PC); PA = sh->sA[w] * PA; }
    }
    float EA = Ae * PA;
    float EC = fmaf(Ce, PA, PC);
    float Rt_ = __fdividef(EA * C_R0, fmaf(EC, C_R0, 1.0f));   // R entering segment

    // ---- phase 3: closed-form outputs; den telescopes ----
    float nn[STEPS];
    float ns = 0.0f;
    float rlPrev = 1.0f;
#pragma unroll
    for (int j = 0; j < STEPS; ++j) {
        float L   = fmaf(Cj[j], Rt_, 1.0f);
        float rlj = __fdividef(1.0f, L);
        sh->lsR[SIDX(seg + j)] = (Aj[j] * Rt_) * rlj;
        float den = L * rlPrev;                        // == 1 + c_j*R_{j-1}
        ns += kk[j] * __logf(den);
        nn[j] = ns;
        rlPrev = rlj;
    }

    // ---- phase 4: two-level prefix sum of per-lane N totals ----
    float S = ns;
#pragma unroll
    for (int o = 1; o < 64; o <<= 1) {
        float Sp = __shfl_up(S, (unsigned)o, 64);
        if (lane >= o) S += Sp;
    }
    if (lane == 63) sh->sS[wid] = S;
    barrier_lgkm();                                    // bar 2
    float PS = C_N0;
#pragma unroll
    for (int w = 0; w < WAVES - 1; ++w) {
        if (w < wid) PS += sh->sS[w];
    }
    float base = PS + (S - ns);
#pragma unroll
    for (int j = 0; j < STEPS; ++j)
        sh->lsN[SIDX(seg + j)] = base + nn[j];

    barrier_lgkm();                                    // bar 3: outputs in LDS
}

// body store: 4 f4 nt stores per WAVE, wave-uniform issue count (exec is
// nonzero in every wave for both q slices; only tid>=~508 lanes mask off)
__device__ __forceinline__ void store_body(
    int b, int tid, const SharedBuf* sh,
    float* __restrict__ Rt, float* __restrict__ Nt)
{
    const size_t g0 = (size_t)b * (T + 1) + 1;
    const int s  = (int)((16 - (g0 & 15)) & 15);
    const int tl = (T - s) & 3;
    const int bodyEnd = T - tl;
#pragma unroll
    for (int q = 0; q < 2; ++q) {
        int m0 = s + q * 2048 + tid * 4;
        if (m0 + 4 <= bodyEnd) {
            f4 r, n;
#pragma unroll
            for (int c = 0; c < 4; ++c) {
                r[c] = sh->lsR[SIDX(m0 + c)];
                n[c] = sh->lsN[SIDX(m0 + c)];
            }
            __builtin_nontemporal_store(r, (f4*)(Rt + g0 + m0));
            __builtin_nontemporal_store(n, (f4*)(Nt + g0 + m0));
        }
    }
}

// head/tail/boundary (non-uniform, issued AFTER the counted wait)
__device__ __forceinline__ void store_edges(
    int b, int tid, const SharedBuf* sh,
    float* __restrict__ Rt, float* __restrict__ Nt)
{
    const size_t g0 = (size_t)b * (T + 1) + 1;
    const int s  = (int)((16 - (g0 & 15)) & 15);
    const int tl = (T - s) & 3;
    const int bodyEnd = T - tl;
    if (tid == 0) {
        __builtin_nontemporal_store(C_R0, Rt + g0 - 1);
        __builtin_nontemporal_store(C_N0, Nt + g0 - 1);
    }
    if (tid < s) {
        __builtin_nontemporal_store(sh->lsR[SIDX(tid)], Rt + g0 + tid);
        __builtin_nontemporal_store(sh->lsN[SIDX(tid)], Nt + g0 + tid);
    }
    if (tid < tl) {
        int m = bodyEnd + tid;
        __builtin_nontemporal_store(sh->lsR[SIDX(m)], Rt + g0 + m);
        __builtin_nontemporal_store(sh->lsN[SIDX(m)], Nt + g0 + m);
    }
}

__global__ __launch_bounds__(NTHR, 4)
void crs_pair_kernel(const float* __restrict__ params,
                     const float* __restrict__ p,
                     const float* __restrict__ dpdt,
                     const float* __restrict__ dtv,
                     float* __restrict__ Rt,
                     float* __restrict__ Nt)
{
    __shared__ SharedBuf sh;

    const int tid  = threadIdx.x;
    const int lane = tid & 63;
    const int wid  = tid >> 6;
    const int b0   = blockIdx.x * 2;
    const int b1   = b0 + 1;

    const float mu0 = params[b0 * 3 + 0];
    const float rc0 = params[b0 * 3 + 1];
    const float rf0 = params[b0 * 3 + 2];
    const float mu1 = params[b1 * 3 + 0];
    const float rc1 = params[b1 * 3 + 1];
    const float rf1 = params[b1 * 3 + 2];
    // drain all prior traffic so the vmcnt ledger below is exact
    asm volatile("s_waitcnt vmcnt(0) lgkmcnt(0)" ::: "memory");

    const int seg = tid * STEPS;
    const float* pr0 = p    + (size_t)b0 * T + seg;
    const float* dr0 = dpdt + (size_t)b0 * T + seg;
    const float* tr0 = dtv  + (size_t)b0 * T + seg;
    const float* pr1 = p    + (size_t)b1 * T + seg;
    const float* dr1 = dpdt + (size_t)b1 * T + seg;
    const float* tr1 = dtv  + (size_t)b1 * T + seg;

    // ---- issue ALL 12 loads; volatile asm cannot be sunk or reordered ----
    f4 a_p0, a_p1, a_d0, a_d1, a_t0, a_t1;
    f4 b_p0, b_p1, b_d0, b_d1, b_t0, b_t1;
    GLOAD  (a_p0, pr0);  GLOAD16(a_p1, pr0);
    GLOAD  (a_d0, dr0);  GLOAD16(a_d1, dr0);
    GLOAD  (a_t0, tr0);  GLOAD16(a_t1, tr0);
    GLOAD  (b_p0, pr1);  GLOAD16(b_p1, pr1);
    GLOAD  (b_d0, dr1);  GLOAD16(b_d1, dr1);
    GLOAD  (b_t0, tr1);  GLOAD16(b_t1, tr1);

    asm volatile("s_waitcnt vmcnt(6)" ::: "memory");   // row0 inputs ready
    __builtin_amdgcn_sched_barrier(0);                 // rule #18: no hoisting

    compute_row(tid, lane, wid, mu0, rc0, rf0,
                a_p0, a_p1, a_d0, a_d1, a_t0, a_t1, &sh);
    store_body(b0, tid, &sh, Rt, Nt);                  // 4 stores per wave

    asm volatile("s_waitcnt vmcnt(4)" ::: "memory");   // row1 loads retired
    __builtin_amdgcn_sched_barrier(0);

    store_edges(b0, tid, &sh, Rt, Nt);

    compute_row(tid, lane, wid, mu1, rc1, rf1,
                b_p0, b_p1, b_d0, b_d1, b_t0, b_t1, &sh);
    store_body(b1, tid, &sh, Rt, Nt);
    store_edges(b1, tid, &sh, Rt, Nt);
}

extern "C" void kernel_launch(void* const* d_in, const int* in_sizes, int n_in,
                              void* d_out, int out_size, void* d_ws, size_t ws_size,
                              hipStream_t stream)
{
    const float* params = (const float*)d_in[0];
    const float* p      = (const float*)d_in[1];
    const float* dpdt   = (const float*)d_in[2];
    const float* dtv    = (const float*)d_in[3];

    float* Rt = (float*)d_out;                       // B*(T+1)
    float* Nt = (float*)d_out + (size_t)B * (T + 1); // B*(T+1)

    crs_pair_kernel<<<B / 2, NTHR, 0, stream>>>(params, p, dpdt, dtv, Rt, Nt);
}